// Round 12
// baseline (482.486 us; speedup 1.0000x reference)
//
#include <hip/hip_runtime.h>

#define NPTS 1500000
#define NVOX 262144
#define BN_EPS 1e-3f
#define PAD 1500160        // NB_L2*128
#define NB_PT 5860
#define NB_L2 11720
#define NBUK 2048          // buckets of 128 voxels

typedef __attribute__((ext_vector_type(8))) short bf16x8;
typedef __attribute__((ext_vector_type(4))) float f32x4;

__device__ __forceinline__ unsigned fkey(float f) {
    unsigned u = __float_as_uint(f);
    return u ^ ((unsigned)(((int)u) >> 31) | 0x80000000u);
}
__device__ __forceinline__ float funkey(unsigned k) {
    unsigned u = (k & 0x80000000u) ? (k ^ 0x80000000u) : ~k;
    return __uint_as_float(u);
}
#define KEY_NEG_INF 0x007FFFFFu

__device__ __forceinline__ float bf2f(unsigned short h) {
    union { unsigned u; float f; } x; x.u = ((unsigned)h) << 16; return x.f;
}
__device__ __forceinline__ unsigned short f2bf(float f) {
    union { float f; unsigned u; } x; x.f = f;
    unsigned r = x.u + 0x7FFFu + ((x.u >> 16) & 1u);
    return (unsigned short)(r >> 16);
}
__device__ __forceinline__ unsigned packbf(float a, float b) {
    return (unsigned)f2bf(a) | ((unsigned)f2bf(b) << 16);
}

__device__ __forceinline__ void make_feat(float x, float y, float z, float w,
                                          float mx, float my, float mz, float* f) {
    const float VS = 0.32f;
    const float PMX = -74.88f, PMY = -74.88f, PMZ = -2.0f;
    f[0] = x; f[1] = y; f[2] = z; f[3] = w;
    f[4] = x - mx; f[5] = y - my; f[6] = z - mz;
    float cx = floorf((x - PMX) / VS);
    float cy = floorf((y - PMY) / VS);
    float cz = floorf((z - PMZ) / VS);
    f[7] = x - (cx * VS + 0.5f * VS + PMX);
    f[8] = y - (cy * VS + 0.5f * VS + PMY);
    f[9] = z - (cz * VS + 0.5f * VS + PMZ);
    f[10] = sqrtf(x * x + y * y + z * z);
}

// all fills/zeros + w2 frag prepack + svid pad
__global__ void k_init(unsigned* __restrict__ okeys, unsigned* __restrict__ xmraw,
                       int* __restrict__ cntv, float* __restrict__ zf,
                       int* __restrict__ svid, const float* __restrict__ w2,
                       uint4* __restrict__ wfrag) {
    long t0 = (long)blockIdx.x * 256 + threadIdx.x;
    long st = (long)gridDim.x * 256;
    uint4 kneg = make_uint4(KEY_NEG_INF, KEY_NEG_INF, KEY_NEG_INF, KEY_NEG_INF);
    for (long i = t0; i < (long)NVOX * 16; i += st) ((uint4*)okeys)[i] = kneg;
    for (long i = t0; i < (long)NVOX * 8; i += st) ((uint4*)xmraw)[i] = kneg;
    for (long i = t0; i < NVOX / 4; i += st) ((int4*)cntv)[i] = make_int4(0, 0, 0, 0);
    for (long i = t0; i < (1024 + 256 * 64 + 256 * 128) / 4; i += st)
        ((float4*)zf)[i] = make_float4(0.f, 0.f, 0.f, 0.f);
    if (t0 < PAD - NPTS) svid[NPTS + t0] = -1;
    if (blockIdx.x == 0 && threadIdx.x < 64) {
        int l = threadIdx.x;
        int lr = l & 15, lk = l >> 4;
        #pragma unroll
        for (int nt = 0; nt < 4; ++nt)
            #pragma unroll
            for (int kt = 0; kt < 2; ++kt) {
                int col = nt * 16 + lr;
                int kb = kt * 32 + lk * 8;
                unsigned u[4];
                #pragma unroll
                for (int j = 0; j < 4; ++j) {
                    float a = w2[(kb + 2 * j) * 64 + col];
                    float b = w2[(kb + 2 * j + 1) * 64 + col];
                    u[j] = packbf(a, b);
                }
                wfrag[(nt * 2 + kt) * 64 + l] = make_uint4(u[0], u[1], u[2], u[3]);
            }
    }
}

__global__ void k_hist(const int* __restrict__ unq, int* __restrict__ cntv) {
    int i = blockIdx.x * blockDim.x + threadIdx.x;
    if (i < NPTS) atomicAdd(&cntv[unq[i]], 1);
}

__global__ void k_scanA(const int* __restrict__ cntv, int* __restrict__ startv,
                        int* __restrict__ bsum) {
    __shared__ int lds[256];
    int t = threadIdx.x;
    int idx4 = blockIdx.x * 256 + t;
    int4 cv = ((const int4*)cntv)[idx4];
    int s0 = cv.x, s1 = s0 + cv.y, s2 = s1 + cv.z, T = s2 + cv.w;
    lds[t] = T;
    __syncthreads();
    for (int o = 1; o < 256; o <<= 1) {
        int v = (t >= o) ? lds[t - o] : 0;
        __syncthreads();
        lds[t] += v;
        __syncthreads();
    }
    int excl = lds[t] - T;
    int4 ov; ov.x = excl; ov.y = excl + s0; ov.z = excl + s1; ov.w = excl + s2;
    ((int4*)startv)[idx4] = ov;
    if (t == 255) bsum[blockIdx.x] = lds[255];
}

// scanC (scanB folded): finalize startv; also init per-bucket append cursors
__global__ void k_scanC(int* __restrict__ startv, int* __restrict__ bukcur,
                        const int* __restrict__ bsum) {
    __shared__ int lds[256];
    int t = threadIdx.x;
    int b = bsum[t];
    lds[t] = b;
    __syncthreads();
    for (int o = 1; o < 256; o <<= 1) {
        int v = (t >= o) ? lds[t - o] : 0;
        __syncthreads();
        lds[t] += v;
        __syncthreads();
    }
    int add = (blockIdx.x > 0) ? lds[blockIdx.x - 1] : 0;
    int idx4 = blockIdx.x * 256 + t;
    int4 v = ((int4*)startv)[idx4];
    v.x += add; v.y += add; v.z += add; v.w += add;
    ((int4*)startv)[idx4] = v;
    int vox0 = idx4 * 4;
    if ((vox0 & 127) == 0) bukcur[vox0 >> 7] = v.x;  // bucket start cursor
}

// C1: append points into coarse buckets (dense per-bucket tail writes)
__global__ void k_bscat(const float* __restrict__ xyz, const float* __restrict__ pf,
                        const int* __restrict__ unq, int* __restrict__ bukcur,
                        float4* __restrict__ stage_p, int* __restrict__ stage_v) {
    int i = blockIdx.x * blockDim.x + threadIdx.x;
    if (i >= NPTS) return;
    int v = unq[i];
    int pos = atomicAdd(&bukcur[v >> 7], 1);
    float4 p;
    p.x = xyz[3 * i + 0]; p.y = xyz[3 * i + 1]; p.z = xyz[3 * i + 2]; p.w = pf[i];
    stage_p[pos] = p;
    stage_v[pos] = v;
}

// C2: per-bucket counting sort into final spts/svid (L2-local dense window)
__global__ __launch_bounds__(256) void k_bsort(
    const float4* __restrict__ stage_p, const int* __restrict__ stage_v,
    const int* __restrict__ startv, float4* __restrict__ spts,
    int* __restrict__ svid) {
    __shared__ int cnt[128];
    int t = threadIdx.x;
    if (t < 128) cnt[t] = 0;
    __syncthreads();
    int b = blockIdx.x;
    int bstart = startv[b << 7];
    int bend = (b == NBUK - 1) ? NPTS : startv[(b + 1) << 7];
    for (int j = bstart + t; j < bend; j += 256) {
        float4 p = stage_p[j];
        int v = stage_v[j];
        int lr = atomicAdd(&cnt[v & 127], 1);
        int pos = startv[v] + lr;
        spts[pos] = p;
        svid[pos] = v;
    }
}

__global__ void k_vmean2(const float4* __restrict__ spts, const int* __restrict__ cntv,
                         const int* __restrict__ startv, float4* __restrict__ vmeanv) {
    int v = blockIdx.x * 256 + threadIdx.x;
    int cnt = cntv[v];
    if (!cnt) return;
    int st = startv[v];
    float sx = 0, sy = 0, sz = 0;
    for (int j = 0; j < cnt; ++j) {
        float4 p = spts[st + j];
        sx += p.x; sy += p.y; sz += p.z;
    }
    float inv = 1.0f / (float)cnt;
    vmeanv[v] = make_float4(sx * inv, sy * inv, sz * inv, 0.f);
}

__device__ __forceinline__ void flush32(int v, float m, bool atom, int c,
                                        unsigned* __restrict__ xm) {
    if ((unsigned)v >= (unsigned)NVOX) return;
    if (atom) atomicMax(&xm[(size_t)v * 32 + c], fkey(m));
    else xm[(size_t)v * 32 + c] = fkey(m);
}
__device__ __forceinline__ void flush64(int v, float m, bool atom, int c,
                                        unsigned* __restrict__ ok) {
    if ((unsigned)v >= (unsigned)NVOX) return;
    if (atom) atomicMax(&ok[(size_t)v * 64 + c], fkey(m));
    else ok[(size_t)v * 64 + c] = fkey(m);
}

// passA: per-wave; 2 lanes/row x 16 ch -> y1 f32; store y1 bf16 to global;
// LDS transpose tile -> segmented scan (unconditional shfl: all lanes active)
__global__ __launch_bounds__(256) void k_passA(
    const float4* __restrict__ spts, const int* __restrict__ svid,
    const float4* __restrict__ vmeanv, const float* __restrict__ w1,
    unsigned* __restrict__ xmraw, unsigned* __restrict__ y1bf,
    float* __restrict__ spart1) {
    __shared__ float ylds[4][32 * 33];
    int t = threadIdx.x;
    int lane = t & 63, wave = t >> 6;
    int rl = lane & 31, half = lane >> 5;
    long grow = (long)blockIdx.x * 128 + wave * 32 + rl;
    int vid = svid[grow];
    float yv[16];
    #pragma unroll
    for (int j = 0; j < 16; ++j) yv[j] = 0.f;
    if (vid >= 0) {
        float4 p = spts[grow];
        float4 vm = vmeanv[vid];
        float f[11];
        make_feat(p.x, p.y, p.z, p.w, vm.x, vm.y, vm.z, f);
        const float4* w1f = (const float4*)w1;
        #pragma unroll
        for (int k = 0; k < 11; ++k) {
            float fk = f[k];
            #pragma unroll
            for (int q = 0; q < 4; ++q) {
                float4 wq = w1f[k * 8 + half * 4 + q];
                yv[4 * q + 0] = fmaf(fk, wq.x, yv[4 * q + 0]);
                yv[4 * q + 1] = fmaf(fk, wq.y, yv[4 * q + 1]);
                yv[4 * q + 2] = fmaf(fk, wq.z, yv[4 * q + 2]);
                yv[4 * q + 3] = fmaf(fk, wq.w, yv[4 * q + 3]);
            }
        }
    }
    {
        unsigned ypk[8];
        #pragma unroll
        for (int q = 0; q < 8; ++q) ypk[q] = packbf(yv[2 * q], yv[2 * q + 1]);
        uint4* yb = (uint4*)y1bf;
        yb[grow * 4 + half * 2 + 0] = *(const uint4*)&ypk[0];
        yb[grow * 4 + half * 2 + 1] = *(const uint4*)&ypk[4];
    }
    float* yw = &ylds[wave][0];
    #pragma unroll
    for (int j = 0; j < 16; ++j) yw[rl * 33 + half * 16 + j] = yv[j];
    asm volatile("s_waitcnt lgkmcnt(0)" ::: "memory");
    __builtin_amdgcn_sched_barrier(0);
    int c = rl;
    int r0 = half * 16;
    float sa = 0.f, sq = 0.f;
    int cur_v = -2; float cur_m = 0.f; bool first = true;
    #pragma unroll
    for (int i = 0; i < 16; ++i) {
        int r = r0 + i;
        float y = yw[r * 33 + c];
        int v = __shfl(vid, r);   // unconditional: all lanes active
        sa += y; sq += y * y;
        if (i == 0) { cur_v = v; cur_m = y; }
        else if (v == cur_v) cur_m = fmaxf(cur_m, y);
        else {
            flush32(cur_v, cur_m, first, c, xmraw);
            first = false; cur_v = v; cur_m = y;
        }
    }
    flush32(cur_v, cur_m, true, c, xmraw);
    sa += __shfl_xor(sa, 32);
    sq += __shfl_xor(sq, 32);
    if (half == 0) {
        int slot = (blockIdx.x * 4 + wave) & 255;
        atomicAdd(&spart1[slot * 64 + c], sa);
        atomicAdd(&spart1[slot * 64 + 32 + c], sq);
    }
}

__global__ void k_fin1(const float* __restrict__ spart1, float* __restrict__ stats,
                       const float* __restrict__ g1, const float* __restrict__ b1) {
    __shared__ float cs[64];
    int t = threadIdx.x;
    float s = 0.f;
    for (int r = 0; r < 256; ++r) s += spart1[r * 64 + t];
    cs[t] = s;
    __syncthreads();
    if (t < 32) {
        float invn = 1.0f / (float)NPTS;
        float mu = cs[t] * invn;
        float var = cs[32 + t] * invn - mu * mu;
        float sc = rsqrtf(var + BN_EPS) * g1[t];
        stats[64 + t] = sc;
        stats[96 + t] = b1[t] - mu * sc;
    }
}

// per-voxel: zxm = packed bf16 of relu(affine(xm))
__global__ void k_xmz(const unsigned* __restrict__ xmraw,
                      const float* __restrict__ stats, unsigned* __restrict__ zxm) {
    int tid = blockIdx.x * 256 + threadIdx.x;  // NVOX*4
    int v = tid >> 2, q = tid & 3;             // channels 8q..8q+7
    uint4 a = ((const uint4*)xmraw)[v * 8 + q * 2];
    uint4 b = ((const uint4*)xmraw)[v * 8 + q * 2 + 1];
    float4 sc0 = ((const float4*)(stats + 64))[q * 2];
    float4 sh0 = ((const float4*)(stats + 96))[q * 2];
    float4 sc1 = ((const float4*)(stats + 64))[q * 2 + 1];
    float4 sh1 = ((const float4*)(stats + 96))[q * 2 + 1];
    uint4 o;
    o.x = packbf(fmaxf(0.f, fmaf(funkey(a.x), sc0.x, sh0.x)),
                 fmaxf(0.f, fmaf(funkey(a.y), sc0.y, sh0.y)));
    o.y = packbf(fmaxf(0.f, fmaf(funkey(a.z), sc0.z, sh0.z)),
                 fmaxf(0.f, fmaf(funkey(a.w), sc0.w, sh0.w)));
    o.z = packbf(fmaxf(0.f, fmaf(funkey(b.x), sc1.x, sh1.x)),
                 fmaxf(0.f, fmaf(funkey(b.y), sc1.y, sh1.y)));
    o.w = packbf(fmaxf(0.f, fmaf(funkey(b.z), sc1.z, sh1.z)),
                 fmaxf(0.f, fmaf(funkey(b.w), sc1.w, sh1.w)));
    ((uint4*)zxm)[v * 4 + q] = o;
}

// k_l2: load y1 bf16 + prepacked zxm -> per-wave Abuf -> MFMA -> y2t (aliased)
// -> boundary-mask segmented max (wave-uniform branch) + BN2 partials.
__global__ __launch_bounds__(256) void k_l2(
    const int* __restrict__ svid, const unsigned* __restrict__ y1bf,
    const unsigned* __restrict__ zxm, const uint4* __restrict__ wfrag,
    const float* __restrict__ stats, float* __restrict__ spart2,
    unsigned* __restrict__ okeys) {
    __shared__ unsigned shbuf[4][1088];   // Abuf [32][32] then y2t [64][17]
    int t = threadIdx.x;
    int lane = t & 63, wave = t >> 6;
    int rl = lane & 31, half = lane >> 5;
    int lr = lane & 15, lk = lane >> 4;
    long brow = (long)blockIdx.x * 128 + wave * 32;
    int vid = svid[brow + rl];
    int vprev = __shfl(vid, (lane + 63) & 63);
    unsigned mask32 = (unsigned)(__ballot(rl > 0 && vid != vprev) & 0xFFFFFFFFull);

    uint4 bw[8];
    #pragma unroll
    for (int q = 0; q < 8; ++q) bw[q] = wfrag[q * 64 + lane];
    uint4 yu0 = ((const uint4*)y1bf)[(brow + rl) * 4 + half * 2];
    uint4 yu1 = ((const uint4*)y1bf)[(brow + rl) * 4 + half * 2 + 1];
    uint4 xa = make_uint4(0, 0, 0, 0), xb = make_uint4(0, 0, 0, 0);
    if (vid >= 0) {
        xa = ((const uint4*)zxm)[(size_t)vid * 4 + half * 2];
        xb = ((const uint4*)zxm)[(size_t)vid * 4 + half * 2 + 1];
    }

    unsigned zpk[8];
    if (vid >= 0) {
        unsigned yw[8] = {yu0.x, yu0.y, yu0.z, yu0.w, yu1.x, yu1.y, yu1.z, yu1.w};
        #pragma unroll
        for (int q = 0; q < 4; ++q) {
            float4 sc = ((const float4*)(stats + 64))[half * 4 + q];
            float4 sh = ((const float4*)(stats + 96))[half * 4 + q];
            float yA = bf2f((unsigned short)(yw[2 * q] & 0xFFFF));
            float yB = bf2f((unsigned short)(yw[2 * q] >> 16));
            float yC = bf2f((unsigned short)(yw[2 * q + 1] & 0xFFFF));
            float yD = bf2f((unsigned short)(yw[2 * q + 1] >> 16));
            zpk[2 * q + 0] = packbf(fmaxf(0.f, fmaf(yA, sc.x, sh.x)),
                                    fmaxf(0.f, fmaf(yB, sc.y, sh.y)));
            zpk[2 * q + 1] = packbf(fmaxf(0.f, fmaf(yC, sc.z, sh.z)),
                                    fmaxf(0.f, fmaf(yD, sc.w, sh.w)));
        }
    } else {
        #pragma unroll
        for (int q = 0; q < 8; ++q) zpk[q] = 0u;
    }
    {
        uint4* arow = (uint4*)&shbuf[wave][rl * 32];
        int sw = rl & 7;
        arow[(2 * half + 0) ^ sw] = *(const uint4*)&zpk[0];
        arow[(2 * half + 1) ^ sw] = *(const uint4*)&zpk[4];
        arow[(4 + 2 * half) ^ sw] = xa;
        arow[(5 + 2 * half) ^ sw] = xb;
    }
    asm volatile("s_waitcnt lgkmcnt(0)" ::: "memory");
    __builtin_amdgcn_sched_barrier(0);

    bf16x8 afr[2][2];
    #pragma unroll
    for (int mt = 0; mt < 2; ++mt)
        #pragma unroll
        for (int kt = 0; kt < 2; ++kt) {
            int riw = mt * 16 + lr;
            uint4 uu = ((const uint4*)&shbuf[wave][riw * 32])[(kt * 4 + lk) ^ (riw & 7)];
            afr[mt][kt] = __builtin_bit_cast(bf16x8, uu);
        }
    asm volatile("s_waitcnt lgkmcnt(0)" ::: "memory");
    __builtin_amdgcn_sched_barrier(0);

    f32x4 acc[2][4];
    #pragma unroll
    for (int mt = 0; mt < 2; ++mt)
        #pragma unroll
        for (int nt = 0; nt < 4; ++nt) {
            acc[mt][nt] = (f32x4){0.f, 0.f, 0.f, 0.f};
            #pragma unroll
            for (int kt = 0; kt < 2; ++kt)
                acc[mt][nt] = __builtin_amdgcn_mfma_f32_16x16x32_bf16(
                    afr[mt][kt], __builtin_bit_cast(bf16x8, bw[nt * 2 + kt]),
                    acc[mt][nt], 0, 0, 0);
        }

    unsigned* y2w = &shbuf[wave][0];
    #pragma unroll
    for (int mt = 0; mt < 2; ++mt)
        #pragma unroll
        for (int nt = 0; nt < 4; ++nt) {
            int col = nt * 16 + lr;
            int w0 = mt * 8 + lk * 2;
            y2w[col * 17 + w0] = packbf(acc[mt][nt][0], acc[mt][nt][1]);
            y2w[col * 17 + w0 + 1] = packbf(acc[mt][nt][2], acc[mt][nt][3]);
        }

    {
        float sa[4] = {0.f, 0.f, 0.f, 0.f}, sq[4] = {0.f, 0.f, 0.f, 0.f};
        #pragma unroll
        for (int mt = 0; mt < 2; ++mt)
            #pragma unroll
            for (int nt = 0; nt < 4; ++nt)
                #pragma unroll
                for (int e = 0; e < 4; ++e) {
                    float v = acc[mt][nt][e];
                    sa[nt] += v; sq[nt] += v * v;
                }
        #pragma unroll
        for (int nt = 0; nt < 4; ++nt) {
            sa[nt] += __shfl_xor(sa[nt], 16); sa[nt] += __shfl_xor(sa[nt], 32);
            sq[nt] += __shfl_xor(sq[nt], 16); sq[nt] += __shfl_xor(sq[nt], 32);
        }
        if (lk == 0) {
            int slot = (blockIdx.x * 4 + wave) & 255;
            #pragma unroll
            for (int nt = 0; nt < 4; ++nt) {
                atomicAdd(&spart2[slot * 128 + nt * 16 + lr], sa[nt]);
                atomicAdd(&spart2[slot * 128 + 64 + nt * 16 + lr], sq[nt]);
            }
        }
    }
    asm volatile("s_waitcnt lgkmcnt(0)" ::: "memory");
    __builtin_amdgcn_sched_barrier(0);

    {
        int c = lane;
        float cur_m = 0.f; bool first = true;
        #pragma unroll
        for (int q = 0; q < 16; ++q) {
            unsigned u = y2w[c * 17 + q];
            #pragma unroll
            for (int e = 0; e < 2; ++e) {
                int r = 2 * q + e;
                float d = bf2f((unsigned short)(e ? (u >> 16) : (u & 0xFFFF)));
                if (r == 0) cur_m = d;
                else if ((mask32 >> r) & 1u) {
                    int v = __shfl(vid, r - 1);   // uniform branch: all lanes active
                    flush64(v, cur_m, first, c, okeys);
                    first = false; cur_m = d;
                } else cur_m = fmaxf(cur_m, d);
            }
        }
        int vlast = __shfl(vid, 31);
        flush64(vlast, cur_m, true, c, okeys);
    }
}

__global__ void k_fin2(const float* __restrict__ spart2, float* __restrict__ stats,
                       const float* __restrict__ g2, const float* __restrict__ b2) {
    __shared__ float cs[128];
    int t = threadIdx.x;
    float s = 0.f;
    for (int r = 0; r < 256; ++r) s += spart2[r * 128 + t];
    cs[t] = s;
    __syncthreads();
    if (t < 64) {
        float invn = 1.0f / (float)NPTS;
        float mu = cs[t] * invn;
        float var = cs[64 + t] * invn - mu * mu;
        float sc = rsqrtf(var + BN_EPS) * g2[t];
        stats[256 + t] = sc;
        stats[320 + t] = b2[t] - mu * sc;
    }
}

__global__ void k_out(unsigned* __restrict__ okeys, const float* __restrict__ stats) {
    int i4 = blockIdx.x * 256 + threadIdx.x;  // < NVOX*16
    uint4 u = ((const uint4*)okeys)[i4];
    int c0 = (i4 & 15) * 4;
    float4 o;
    o.x = fmaxf(0.f, fmaf(funkey(u.x), stats[256 + c0 + 0], stats[320 + c0 + 0]));
    o.y = fmaxf(0.f, fmaf(funkey(u.y), stats[256 + c0 + 1], stats[320 + c0 + 1]));
    o.z = fmaxf(0.f, fmaf(funkey(u.z), stats[256 + c0 + 2], stats[320 + c0 + 2]));
    o.w = fmaxf(0.f, fmaf(funkey(u.w), stats[256 + c0 + 3], stats[320 + c0 + 3]));
    ((float4*)okeys)[i4] = o;
}

extern "C" void kernel_launch(void* const* d_in, const int* in_sizes, int n_in,
                              void* d_out, int out_size, void* d_ws, size_t ws_size,
                              hipStream_t stream) {
    const float* xyz = (const float*)d_in[0];
    const float* pf  = (const float*)d_in[1];
    const float* w1  = (const float*)d_in[2];
    const float* g1  = (const float*)d_in[3];
    const float* b1  = (const float*)d_in[4];
    const float* w2  = (const float*)d_in[5];
    const float* g2  = (const float*)d_in[6];
    const float* b2  = (const float*)d_in[7];
    const int*   unq = (const int*)d_in[8];

    float4* spts     = (float4*)d_ws;                        // PAD float4 (24 MB)
    float4* vmeanv   = spts + PAD;                           // NVOX float4 (4 MB)
    int* svid        = (int*)(vmeanv + NVOX);                // PAD ints (6 MB)
    unsigned* xmraw  = (unsigned*)(svid + PAD);              // NVOX*32 f32-fkeys (32 MB)
    int* cntv        = (int*)(xmraw + (size_t)NVOX * 32);    // NVOX
    int* startv      = cntv + NVOX;                          // NVOX
    int* bukcur      = startv + NVOX;                        // NBUK (2048)
    int* bsum        = bukcur + NVOX;                        // 256
    float* stats     = (float*)(bsum + 256);                 // 1024
    float* spart1    = stats + 1024;                         // 256*64
    float* spart2    = spart1 + 256 * 64;                    // 256*128
    uint4* wfrag     = (uint4*)(spart2 + 256 * 128);         // 8*64 uint4
    unsigned* y1bf   = (unsigned*)(wfrag + 512);             // PAD*16 uints (96 MB)
    // staging for bucketed sort ALIASES y1bf (dead until k_passA writes it)
    float4* stage_p  = (float4*)y1bf;                        // PAD float4
    int* stage_v     = (int*)(stage_p + PAD);                // PAD ints
    // zxm (16 MB) aliases spts? NO — spts live through k_l2's producer passA.
    // zxm aliases stage region's tail? stage dead after k_bsort, but y1bf
    // overwrites it. Keep zxm aliasing spts-region REPLACED: spts is live.
    // Use the proven r11 layout: zxm aliases nothing new — place after stage
    // within y1bf? y1bf live in k_l2. -> keep r11 solution: zxm = spts alias
    // is INVALID now? r11: spts dead after k_passA; k_xmz after k_fin1 which
    // is after k_passA -> still true here. spts dead after k_passA. OK.
    unsigned* zxm    = (unsigned*)spts;

    unsigned* okeys = (unsigned*)d_out;

    k_init<<<2048, 256, 0, stream>>>(okeys, xmraw, cntv, stats, svid, w2, wfrag);
    k_hist<<<NB_PT, 256, 0, stream>>>(unq, cntv);
    k_scanA<<<256, 256, 0, stream>>>(cntv, startv, bsum);
    k_scanC<<<256, 256, 0, stream>>>(startv, bukcur, bsum);
    k_bscat<<<NB_PT, 256, 0, stream>>>(xyz, pf, unq, bukcur, stage_p, stage_v);
    k_bsort<<<NBUK, 256, 0, stream>>>(stage_p, stage_v, startv, spts, svid);
    k_vmean2<<<NVOX / 256, 256, 0, stream>>>(spts, cntv, startv, vmeanv);
    k_passA<<<NB_L2, 256, 0, stream>>>(spts, svid, vmeanv, w1, xmraw, y1bf, spart1);
    k_fin1<<<1, 64, 0, stream>>>(spart1, stats, g1, b1);
    k_xmz<<<NVOX * 4 / 256, 256, 0, stream>>>(xmraw, stats, zxm);
    k_l2<<<NB_L2, 256, 0, stream>>>(svid, y1bf, zxm, wfrag, stats, spart2, okeys);
    k_fin2<<<1, 128, 0, stream>>>(spart2, stats, g2, b2);
    k_out<<<NVOX * 16 / 256, 256, 0, stream>>>(okeys, stats);
}

// Round 13
// 434.076 us; speedup vs baseline: 1.1115x; 1.1115x over previous
//
#include <hip/hip_runtime.h>

#define NPTS 1500000
#define NVOX 262144
#define BN_EPS 1e-3f
#define PAD 1500160        // NB_L2*128
#define NB_PT 5860
#define NB_L2 11720

typedef __attribute__((ext_vector_type(8))) short bf16x8;
typedef __attribute__((ext_vector_type(4))) float f32x4;

__device__ __forceinline__ unsigned fkey(float f) {
    unsigned u = __float_as_uint(f);
    return u ^ ((unsigned)(((int)u) >> 31) | 0x80000000u);
}
__device__ __forceinline__ float funkey(unsigned k) {
    unsigned u = (k & 0x80000000u) ? (k ^ 0x80000000u) : ~k;
    return __uint_as_float(u);
}
#define KEY_NEG_INF 0x007FFFFFu

__device__ __forceinline__ float bf2f(unsigned short h) {
    union { unsigned u; float f; } x; x.u = ((unsigned)h) << 16; return x.f;
}
__device__ __forceinline__ unsigned short f2bf(float f) {
    union { float f; unsigned u; } x; x.f = f;
    unsigned r = x.u + 0x7FFFu + ((x.u >> 16) & 1u);
    return (unsigned short)(r >> 16);
}
__device__ __forceinline__ unsigned packbf(float a, float b) {
    return (unsigned)f2bf(a) | ((unsigned)f2bf(b) << 16);
}

__device__ __forceinline__ void make_feat(float x, float y, float z, float w,
                                          float mx, float my, float mz, float* f) {
    const float VS = 0.32f;
    const float PMX = -74.88f, PMY = -74.88f, PMZ = -2.0f;
    f[0] = x; f[1] = y; f[2] = z; f[3] = w;
    f[4] = x - mx; f[5] = y - my; f[6] = z - mz;
    float cx = floorf((x - PMX) / VS);
    float cy = floorf((y - PMY) / VS);
    float cz = floorf((z - PMZ) / VS);
    f[7] = x - (cx * VS + 0.5f * VS + PMX);
    f[8] = y - (cy * VS + 0.5f * VS + PMY);
    f[9] = z - (cz * VS + 0.5f * VS + PMZ);
    f[10] = sqrtf(x * x + y * y + z * z);
}

// all fills/zeros + w2 frag prepack + svid pad
__global__ void k_init(unsigned* __restrict__ okeys, unsigned* __restrict__ xmraw,
                       int* __restrict__ cntv, float* __restrict__ zf,
                       int* __restrict__ svid, const float* __restrict__ w2,
                       uint4* __restrict__ wfrag) {
    long t0 = (long)blockIdx.x * 256 + threadIdx.x;
    long st = (long)gridDim.x * 256;
    uint4 kneg = make_uint4(KEY_NEG_INF, KEY_NEG_INF, KEY_NEG_INF, KEY_NEG_INF);
    for (long i = t0; i < (long)NVOX * 16; i += st) ((uint4*)okeys)[i] = kneg;
    for (long i = t0; i < (long)NVOX * 8; i += st) ((uint4*)xmraw)[i] = kneg;
    for (long i = t0; i < NVOX / 4; i += st) ((int4*)cntv)[i] = make_int4(0, 0, 0, 0);
    for (long i = t0; i < (1024 + 256 * 64 + 256 * 128) / 4; i += st)
        ((float4*)zf)[i] = make_float4(0.f, 0.f, 0.f, 0.f);
    if (t0 < PAD - NPTS) svid[NPTS + t0] = -1;
    if (blockIdx.x == 0 && threadIdx.x < 64) {
        int l = threadIdx.x;
        int lr = l & 15, lk = l >> 4;
        #pragma unroll
        for (int nt = 0; nt < 4; ++nt)
            #pragma unroll
            for (int kt = 0; kt < 2; ++kt) {
                int col = nt * 16 + lr;
                int kb = kt * 32 + lk * 8;
                unsigned u[4];
                #pragma unroll
                for (int j = 0; j < 4; ++j) {
                    float a = w2[(kb + 2 * j) * 64 + col];
                    float b = w2[(kb + 2 * j + 1) * 64 + col];
                    u[j] = packbf(a, b);
                }
                wfrag[(nt * 2 + kt) * 64 + l] = make_uint4(u[0], u[1], u[2], u[3]);
            }
    }
}

__global__ void k_hist(const int* __restrict__ unq, int* __restrict__ cntv) {
    int i = blockIdx.x * blockDim.x + threadIdx.x;
    if (i < NPTS) atomicAdd(&cntv[unq[i]], 1);
}

__global__ void k_scanA(const int* __restrict__ cntv, int* __restrict__ startv,
                        int* __restrict__ bsum) {
    __shared__ int lds[256];
    int t = threadIdx.x;
    int idx4 = blockIdx.x * 256 + t;
    int4 cv = ((const int4*)cntv)[idx4];
    int s0 = cv.x, s1 = s0 + cv.y, s2 = s1 + cv.z, T = s2 + cv.w;
    lds[t] = T;
    __syncthreads();
    for (int o = 1; o < 256; o <<= 1) {
        int v = (t >= o) ? lds[t - o] : 0;
        __syncthreads();
        lds[t] += v;
        __syncthreads();
    }
    int excl = lds[t] - T;
    int4 ov; ov.x = excl; ov.y = excl + s0; ov.z = excl + s1; ov.w = excl + s2;
    ((int4*)startv)[idx4] = ov;
    if (t == 255) bsum[blockIdx.x] = lds[255];
}

// scanC (scanB folded): every block redundantly scans the 256 bsums
__global__ void k_scanC(int* __restrict__ startv, int* __restrict__ offv,
                        const int* __restrict__ bsum) {
    __shared__ int lds[256];
    int t = threadIdx.x;
    int b = bsum[t];
    lds[t] = b;
    __syncthreads();
    for (int o = 1; o < 256; o <<= 1) {
        int v = (t >= o) ? lds[t - o] : 0;
        __syncthreads();
        lds[t] += v;
        __syncthreads();
    }
    int add = (blockIdx.x > 0) ? lds[blockIdx.x - 1] : 0;
    int idx4 = blockIdx.x * 256 + t;
    int4 v = ((int4*)startv)[idx4];
    v.x += add; v.y += add; v.z += add; v.w += add;
    ((int4*)startv)[idx4] = v;
    ((int4*)offv)[idx4] = v;
}

// scatter ONLY a 4B index per point (5x less random-write payload than spts+svid)
__global__ void k_scatteridx(const int* __restrict__ unq, int* __restrict__ offv,
                             int* __restrict__ sidx) {
    int i = blockIdx.x * blockDim.x + threadIdx.x;
    if (i >= NPTS) return;
    int v = unq[i];
    int pos = atomicAdd(&offv[v], 1);
    sidx[pos] = i;
}

// dense svid fill: thread per voxel writes its contiguous range
__global__ void k_fillvid(const int* __restrict__ cntv, const int* __restrict__ startv,
                          int* __restrict__ svid) {
    int v = blockIdx.x * 256 + threadIdx.x;
    int cnt = cntv[v];
    int st = startv[v];
    for (int j = 0; j < cnt; ++j) svid[st + j] = v;
}

// thread-per-voxel mean, gathering xyz via sidx (L2/L3-resident)
__global__ void k_vmean2(const float* __restrict__ xyz, const int* __restrict__ sidx,
                         const int* __restrict__ cntv, const int* __restrict__ startv,
                         float4* __restrict__ vmeanv) {
    int v = blockIdx.x * 256 + threadIdx.x;
    int cnt = cntv[v];
    if (!cnt) return;
    int st = startv[v];
    float sx = 0, sy = 0, sz = 0;
    for (int j = 0; j < cnt; ++j) {
        int idx = sidx[st + j];
        sx += xyz[3 * idx + 0]; sy += xyz[3 * idx + 1]; sz += xyz[3 * idx + 2];
    }
    float inv = 1.0f / (float)cnt;
    vmeanv[v] = make_float4(sx * inv, sy * inv, sz * inv, 0.f);
}

__device__ __forceinline__ void flush32(int v, float m, bool atom, int c,
                                        unsigned* __restrict__ xm) {
    if ((unsigned)v >= (unsigned)NVOX) return;
    if (atom) atomicMax(&xm[(size_t)v * 32 + c], fkey(m));
    else xm[(size_t)v * 32 + c] = fkey(m);
}
__device__ __forceinline__ void flush64(int v, float m, bool atom, int c,
                                        unsigned* __restrict__ ok) {
    if ((unsigned)v >= (unsigned)NVOX) return;
    if (atom) atomicMax(&ok[(size_t)v * 64 + c], fkey(m));
    else ok[(size_t)v * 64 + c] = fkey(m);
}

// passA: per-wave; 2 lanes/row x 16 ch -> y1 f32 (xyz gathered via sidx);
// store y1 bf16; LDS transpose tile -> segmented scan (unconditional shfl)
__global__ __launch_bounds__(256) void k_passA(
    const float* __restrict__ xyz, const float* __restrict__ pf,
    const int* __restrict__ sidx, const int* __restrict__ svid,
    const float4* __restrict__ vmeanv, const float* __restrict__ w1,
    unsigned* __restrict__ xmraw, unsigned* __restrict__ y1bf,
    float* __restrict__ spart1) {
    __shared__ float ylds[4][32 * 33];
    int t = threadIdx.x;
    int lane = t & 63, wave = t >> 6;
    int rl = lane & 31, half = lane >> 5;
    long grow = (long)blockIdx.x * 128 + wave * 32 + rl;
    int vid = svid[grow];
    float yv[16];
    #pragma unroll
    for (int j = 0; j < 16; ++j) yv[j] = 0.f;
    if (vid >= 0) {
        int idx = sidx[grow];
        float px = xyz[3 * idx + 0], py = xyz[3 * idx + 1], pz = xyz[3 * idx + 2];
        float pw = pf[idx];
        float4 vm = vmeanv[vid];
        float f[11];
        make_feat(px, py, pz, pw, vm.x, vm.y, vm.z, f);
        const float4* w1f = (const float4*)w1;
        #pragma unroll
        for (int k = 0; k < 11; ++k) {
            float fk = f[k];
            #pragma unroll
            for (int q = 0; q < 4; ++q) {
                float4 wq = w1f[k * 8 + half * 4 + q];
                yv[4 * q + 0] = fmaf(fk, wq.x, yv[4 * q + 0]);
                yv[4 * q + 1] = fmaf(fk, wq.y, yv[4 * q + 1]);
                yv[4 * q + 2] = fmaf(fk, wq.z, yv[4 * q + 2]);
                yv[4 * q + 3] = fmaf(fk, wq.w, yv[4 * q + 3]);
            }
        }
    }
    {
        unsigned ypk[8];
        #pragma unroll
        for (int q = 0; q < 8; ++q) ypk[q] = packbf(yv[2 * q], yv[2 * q + 1]);
        uint4* yb = (uint4*)y1bf;
        yb[grow * 4 + half * 2 + 0] = *(const uint4*)&ypk[0];
        yb[grow * 4 + half * 2 + 1] = *(const uint4*)&ypk[4];
    }
    float* yw = &ylds[wave][0];
    #pragma unroll
    for (int j = 0; j < 16; ++j) yw[rl * 33 + half * 16 + j] = yv[j];
    asm volatile("s_waitcnt lgkmcnt(0)" ::: "memory");
    __builtin_amdgcn_sched_barrier(0);
    int c = rl;
    int r0 = half * 16;
    float sa = 0.f, sq = 0.f;
    int cur_v = -2; float cur_m = 0.f; bool first = true;
    #pragma unroll
    for (int i = 0; i < 16; ++i) {
        int r = r0 + i;
        float y = yw[r * 33 + c];
        int v = __shfl(vid, r);   // unconditional: all lanes active
        sa += y; sq += y * y;
        if (i == 0) { cur_v = v; cur_m = y; }
        else if (v == cur_v) cur_m = fmaxf(cur_m, y);
        else {
            flush32(cur_v, cur_m, first, c, xmraw);
            first = false; cur_v = v; cur_m = y;
        }
    }
    flush32(cur_v, cur_m, true, c, xmraw);
    sa += __shfl_xor(sa, 32);
    sq += __shfl_xor(sq, 32);
    if (half == 0) {
        int slot = (blockIdx.x * 4 + wave) & 255;
        atomicAdd(&spart1[slot * 64 + c], sa);
        atomicAdd(&spart1[slot * 64 + 32 + c], sq);
    }
}

__global__ void k_fin1(const float* __restrict__ spart1, float* __restrict__ stats,
                       const float* __restrict__ g1, const float* __restrict__ b1) {
    __shared__ float cs[64];
    int t = threadIdx.x;
    float s = 0.f;
    for (int r = 0; r < 256; ++r) s += spart1[r * 64 + t];
    cs[t] = s;
    __syncthreads();
    if (t < 32) {
        float invn = 1.0f / (float)NPTS;
        float mu = cs[t] * invn;
        float var = cs[32 + t] * invn - mu * mu;
        float sc = rsqrtf(var + BN_EPS) * g1[t];
        stats[64 + t] = sc;
        stats[96 + t] = b1[t] - mu * sc;
    }
}

// per-voxel: zxm = packed bf16 of relu(affine(xm))
__global__ void k_xmz(const unsigned* __restrict__ xmraw,
                      const float* __restrict__ stats, unsigned* __restrict__ zxm) {
    int tid = blockIdx.x * 256 + threadIdx.x;  // NVOX*4
    int v = tid >> 2, q = tid & 3;             // channels 8q..8q+7
    uint4 a = ((const uint4*)xmraw)[v * 8 + q * 2];
    uint4 b = ((const uint4*)xmraw)[v * 8 + q * 2 + 1];
    float4 sc0 = ((const float4*)(stats + 64))[q * 2];
    float4 sh0 = ((const float4*)(stats + 96))[q * 2];
    float4 sc1 = ((const float4*)(stats + 64))[q * 2 + 1];
    float4 sh1 = ((const float4*)(stats + 96))[q * 2 + 1];
    uint4 o;
    o.x = packbf(fmaxf(0.f, fmaf(funkey(a.x), sc0.x, sh0.x)),
                 fmaxf(0.f, fmaf(funkey(a.y), sc0.y, sh0.y)));
    o.y = packbf(fmaxf(0.f, fmaf(funkey(a.z), sc0.z, sh0.z)),
                 fmaxf(0.f, fmaf(funkey(a.w), sc0.w, sh0.w)));
    o.z = packbf(fmaxf(0.f, fmaf(funkey(b.x), sc1.x, sh1.x)),
                 fmaxf(0.f, fmaf(funkey(b.y), sc1.y, sh1.y)));
    o.w = packbf(fmaxf(0.f, fmaf(funkey(b.z), sc1.z, sh1.z)),
                 fmaxf(0.f, fmaf(funkey(b.w), sc1.w, sh1.w)));
    ((uint4*)zxm)[v * 4 + q] = o;
}

// k_l2: load y1 bf16 + prepacked zxm -> per-wave Abuf -> MFMA -> y2t (aliased)
// -> boundary-mask segmented max (wave-uniform branch) + BN2 partials.
__global__ __launch_bounds__(256) void k_l2(
    const int* __restrict__ svid, const unsigned* __restrict__ y1bf,
    const unsigned* __restrict__ zxm, const uint4* __restrict__ wfrag,
    const float* __restrict__ stats, float* __restrict__ spart2,
    unsigned* __restrict__ okeys) {
    __shared__ unsigned shbuf[4][1088];   // Abuf [32][32] then y2t [64][17]
    int t = threadIdx.x;
    int lane = t & 63, wave = t >> 6;
    int rl = lane & 31, half = lane >> 5;
    int lr = lane & 15, lk = lane >> 4;
    long brow = (long)blockIdx.x * 128 + wave * 32;
    int vid = svid[brow + rl];
    int vprev = __shfl(vid, (lane + 63) & 63);
    unsigned mask32 = (unsigned)(__ballot(rl > 0 && vid != vprev) & 0xFFFFFFFFull);

    uint4 bw[8];
    #pragma unroll
    for (int q = 0; q < 8; ++q) bw[q] = wfrag[q * 64 + lane];
    uint4 yu0 = ((const uint4*)y1bf)[(brow + rl) * 4 + half * 2];
    uint4 yu1 = ((const uint4*)y1bf)[(brow + rl) * 4 + half * 2 + 1];
    uint4 xa = make_uint4(0, 0, 0, 0), xb = make_uint4(0, 0, 0, 0);
    if (vid >= 0) {
        xa = ((const uint4*)zxm)[(size_t)vid * 4 + half * 2];
        xb = ((const uint4*)zxm)[(size_t)vid * 4 + half * 2 + 1];
    }

    unsigned zpk[8];
    if (vid >= 0) {
        unsigned yw[8] = {yu0.x, yu0.y, yu0.z, yu0.w, yu1.x, yu1.y, yu1.z, yu1.w};
        #pragma unroll
        for (int q = 0; q < 4; ++q) {
            float4 sc = ((const float4*)(stats + 64))[half * 4 + q];
            float4 sh = ((const float4*)(stats + 96))[half * 4 + q];
            float yA = bf2f((unsigned short)(yw[2 * q] & 0xFFFF));
            float yB = bf2f((unsigned short)(yw[2 * q] >> 16));
            float yC = bf2f((unsigned short)(yw[2 * q + 1] & 0xFFFF));
            float yD = bf2f((unsigned short)(yw[2 * q + 1] >> 16));
            zpk[2 * q + 0] = packbf(fmaxf(0.f, fmaf(yA, sc.x, sh.x)),
                                    fmaxf(0.f, fmaf(yB, sc.y, sh.y)));
            zpk[2 * q + 1] = packbf(fmaxf(0.f, fmaf(yC, sc.z, sh.z)),
                                    fmaxf(0.f, fmaf(yD, sc.w, sh.w)));
        }
    } else {
        #pragma unroll
        for (int q = 0; q < 8; ++q) zpk[q] = 0u;
    }
    {
        uint4* arow = (uint4*)&shbuf[wave][rl * 32];
        int sw = rl & 7;
        arow[(2 * half + 0) ^ sw] = *(const uint4*)&zpk[0];
        arow[(2 * half + 1) ^ sw] = *(const uint4*)&zpk[4];
        arow[(4 + 2 * half) ^ sw] = xa;
        arow[(5 + 2 * half) ^ sw] = xb;
    }
    asm volatile("s_waitcnt lgkmcnt(0)" ::: "memory");
    __builtin_amdgcn_sched_barrier(0);

    bf16x8 afr[2][2];
    #pragma unroll
    for (int mt = 0; mt < 2; ++mt)
        #pragma unroll
        for (int kt = 0; kt < 2; ++kt) {
            int riw = mt * 16 + lr;
            uint4 uu = ((const uint4*)&shbuf[wave][riw * 32])[(kt * 4 + lk) ^ (riw & 7)];
            afr[mt][kt] = __builtin_bit_cast(bf16x8, uu);
        }
    asm volatile("s_waitcnt lgkmcnt(0)" ::: "memory");
    __builtin_amdgcn_sched_barrier(0);

    f32x4 acc[2][4];
    #pragma unroll
    for (int mt = 0; mt < 2; ++mt)
        #pragma unroll
        for (int nt = 0; nt < 4; ++nt) {
            acc[mt][nt] = (f32x4){0.f, 0.f, 0.f, 0.f};
            #pragma unroll
            for (int kt = 0; kt < 2; ++kt)
                acc[mt][nt] = __builtin_amdgcn_mfma_f32_16x16x32_bf16(
                    afr[mt][kt], __builtin_bit_cast(bf16x8, bw[nt * 2 + kt]),
                    acc[mt][nt], 0, 0, 0);
        }

    unsigned* y2w = &shbuf[wave][0];
    #pragma unroll
    for (int mt = 0; mt < 2; ++mt)
        #pragma unroll
        for (int nt = 0; nt < 4; ++nt) {
            int col = nt * 16 + lr;
            int w0 = mt * 8 + lk * 2;
            y2w[col * 17 + w0] = packbf(acc[mt][nt][0], acc[mt][nt][1]);
            y2w[col * 17 + w0 + 1] = packbf(acc[mt][nt][2], acc[mt][nt][3]);
        }

    {
        float sa[4] = {0.f, 0.f, 0.f, 0.f}, sq[4] = {0.f, 0.f, 0.f, 0.f};
        #pragma unroll
        for (int mt = 0; mt < 2; ++mt)
            #pragma unroll
            for (int nt = 0; nt < 4; ++nt)
                #pragma unroll
                for (int e = 0; e < 4; ++e) {
                    float v = acc[mt][nt][e];
                    sa[nt] += v; sq[nt] += v * v;
                }
        #pragma unroll
        for (int nt = 0; nt < 4; ++nt) {
            sa[nt] += __shfl_xor(sa[nt], 16); sa[nt] += __shfl_xor(sa[nt], 32);
            sq[nt] += __shfl_xor(sq[nt], 16); sq[nt] += __shfl_xor(sq[nt], 32);
        }
        if (lk == 0) {
            int slot = (blockIdx.x * 4 + wave) & 255;
            #pragma unroll
            for (int nt = 0; nt < 4; ++nt) {
                atomicAdd(&spart2[slot * 128 + nt * 16 + lr], sa[nt]);
                atomicAdd(&spart2[slot * 128 + 64 + nt * 16 + lr], sq[nt]);
            }
        }
    }
    asm volatile("s_waitcnt lgkmcnt(0)" ::: "memory");
    __builtin_amdgcn_sched_barrier(0);

    {
        int c = lane;
        float cur_m = 0.f; bool first = true;
        #pragma unroll
        for (int q = 0; q < 16; ++q) {
            unsigned u = y2w[c * 17 + q];
            #pragma unroll
            for (int e = 0; e < 2; ++e) {
                int r = 2 * q + e;
                float d = bf2f((unsigned short)(e ? (u >> 16) : (u & 0xFFFF)));
                if (r == 0) cur_m = d;
                else if ((mask32 >> r) & 1u) {
                    int v = __shfl(vid, r - 1);   // uniform branch: all lanes active
                    flush64(v, cur_m, first, c, okeys);
                    first = false; cur_m = d;
                } else cur_m = fmaxf(cur_m, d);
            }
        }
        int vlast = __shfl(vid, 31);
        flush64(vlast, cur_m, true, c, okeys);
    }
}

__global__ void k_fin2(const float* __restrict__ spart2, float* __restrict__ stats,
                       const float* __restrict__ g2, const float* __restrict__ b2) {
    __shared__ float cs[128];
    int t = threadIdx.x;
    float s = 0.f;
    for (int r = 0; r < 256; ++r) s += spart2[r * 128 + t];
    cs[t] = s;
    __syncthreads();
    if (t < 64) {
        float invn = 1.0f / (float)NPTS;
        float mu = cs[t] * invn;
        float var = cs[64 + t] * invn - mu * mu;
        float sc = rsqrtf(var + BN_EPS) * g2[t];
        stats[256 + t] = sc;
        stats[320 + t] = b2[t] - mu * sc;
    }
}

__global__ void k_out(unsigned* __restrict__ okeys, const float* __restrict__ stats) {
    int i4 = blockIdx.x * 256 + threadIdx.x;  // < NVOX*16
    uint4 u = ((const uint4*)okeys)[i4];
    int c0 = (i4 & 15) * 4;
    float4 o;
    o.x = fmaxf(0.f, fmaf(funkey(u.x), stats[256 + c0 + 0], stats[320 + c0 + 0]));
    o.y = fmaxf(0.f, fmaf(funkey(u.y), stats[256 + c0 + 1], stats[320 + c0 + 1]));
    o.z = fmaxf(0.f, fmaf(funkey(u.z), stats[256 + c0 + 2], stats[320 + c0 + 2]));
    o.w = fmaxf(0.f, fmaf(funkey(u.w), stats[256 + c0 + 3], stats[320 + c0 + 3]));
    ((float4*)okeys)[i4] = o;
}

extern "C" void kernel_launch(void* const* d_in, const int* in_sizes, int n_in,
                              void* d_out, int out_size, void* d_ws, size_t ws_size,
                              hipStream_t stream) {
    const float* xyz = (const float*)d_in[0];
    const float* pf  = (const float*)d_in[1];
    const float* w1  = (const float*)d_in[2];
    const float* g1  = (const float*)d_in[3];
    const float* b1  = (const float*)d_in[4];
    const float* w2  = (const float*)d_in[5];
    const float* g2  = (const float*)d_in[6];
    const float* b2  = (const float*)d_in[7];
    const int*   unq = (const int*)d_in[8];

    int* sidx        = (int*)d_ws;                           // PAD ints (6 MB)
    int* svid        = sidx + PAD;                           // PAD ints (6 MB)
    float4* vmeanv   = (float4*)(svid + PAD);                // NVOX float4 (4 MB)
    unsigned* xmraw  = (unsigned*)(vmeanv + NVOX);           // NVOX*32 (32 MB)
    unsigned* zxm    = xmraw + (size_t)NVOX * 32;            // NVOX*16 (16 MB)
    int* cntv        = (int*)(zxm + (size_t)NVOX * 16);      // NVOX
    int* startv      = cntv + NVOX;                          // NVOX
    int* offv        = startv + NVOX;                        // NVOX
    int* bsum        = offv + NVOX;                          // 256
    float* stats     = (float*)(bsum + 256);                 // 1024
    float* spart1    = stats + 1024;                         // 256*64
    float* spart2    = spart1 + 256 * 64;                    // 256*128
    uint4* wfrag     = (uint4*)(spart2 + 256 * 128);         // 8*64 uint4
    unsigned* y1bf   = (unsigned*)(wfrag + 512);             // PAD*16 uints (96 MB)
    // total ~163 MB, within the round-8-proven footprint

    unsigned* okeys = (unsigned*)d_out;

    k_init<<<2048, 256, 0, stream>>>(okeys, xmraw, cntv, stats, svid, w2, wfrag);
    k_hist<<<NB_PT, 256, 0, stream>>>(unq, cntv);
    k_scanA<<<256, 256, 0, stream>>>(cntv, startv, bsum);
    k_scanC<<<256, 256, 0, stream>>>(startv, offv, bsum);
    k_scatteridx<<<NB_PT, 256, 0, stream>>>(unq, offv, sidx);
    k_fillvid<<<NVOX / 256, 256, 0, stream>>>(cntv, startv, svid);
    k_vmean2<<<NVOX / 256, 256, 0, stream>>>(xyz, sidx, cntv, startv, vmeanv);
    k_passA<<<NB_L2, 256, 0, stream>>>(xyz, pf, sidx, svid, vmeanv, w1, xmraw,
                                       y1bf, spart1);
    k_fin1<<<1, 64, 0, stream>>>(spart1, stats, g1, b1);
    k_xmz<<<NVOX * 4 / 256, 256, 0, stream>>>(xmraw, stats, zxm);
    k_l2<<<NB_L2, 256, 0, stream>>>(svid, y1bf, zxm, wfrag, stats, spart2, okeys);
    k_fin2<<<1, 128, 0, stream>>>(spart2, stats, g2, b2);
    k_out<<<NVOX * 16 / 256, 256, 0, stream>>>(okeys, stats);
}

// Round 14
// 365.701 us; speedup vs baseline: 1.3193x; 1.1870x over previous
//
#include <hip/hip_runtime.h>

#define NPTS 1500000
#define NVOX 262144
#define BN_EPS 1e-3f
#define PAD 1500160        // NB_L2*128
#define NB_PT 5860
#define NB_L2 11720

typedef __attribute__((ext_vector_type(8))) short bf16x8;
typedef __attribute__((ext_vector_type(4))) float f32x4;

__device__ __forceinline__ unsigned fkey(float f) {
    unsigned u = __float_as_uint(f);
    return u ^ ((unsigned)(((int)u) >> 31) | 0x80000000u);
}
__device__ __forceinline__ float funkey(unsigned k) {
    unsigned u = (k & 0x80000000u) ? (k ^ 0x80000000u) : ~k;
    return __uint_as_float(u);
}
#define KEY_NEG_INF 0x007FFFFFu

__device__ __forceinline__ float bf2f(unsigned short h) {
    union { unsigned u; float f; } x; x.u = ((unsigned)h) << 16; return x.f;
}
__device__ __forceinline__ unsigned short f2bf(float f) {
    union { float f; unsigned u; } x; x.f = f;
    unsigned r = x.u + 0x7FFFu + ((x.u >> 16) & 1u);
    return (unsigned short)(r >> 16);
}
__device__ __forceinline__ unsigned packbf(float a, float b) {
    return (unsigned)f2bf(a) | ((unsigned)f2bf(b) << 16);
}

__device__ __forceinline__ void make_feat(float x, float y, float z, float w,
                                          float mx, float my, float mz, float* f) {
    const float VS = 0.32f;
    const float PMX = -74.88f, PMY = -74.88f, PMZ = -2.0f;
    f[0] = x; f[1] = y; f[2] = z; f[3] = w;
    f[4] = x - mx; f[5] = y - my; f[6] = z - mz;
    float cx = floorf((x - PMX) / VS);
    float cy = floorf((y - PMY) / VS);
    float cz = floorf((z - PMZ) / VS);
    f[7] = x - (cx * VS + 0.5f * VS + PMX);
    f[8] = y - (cy * VS + 0.5f * VS + PMY);
    f[9] = z - (cz * VS + 0.5f * VS + PMZ);
    f[10] = sqrtf(x * x + y * y + z * z);
}

// all fills/zeros + w2 frag prepack + svid pad
__global__ void k_init(unsigned* __restrict__ okeys, unsigned* __restrict__ xmraw,
                       int* __restrict__ cntv, float* __restrict__ zf,
                       int* __restrict__ svid, const float* __restrict__ w2,
                       uint4* __restrict__ wfrag) {
    long t0 = (long)blockIdx.x * 256 + threadIdx.x;
    long st = (long)gridDim.x * 256;
    uint4 kneg = make_uint4(KEY_NEG_INF, KEY_NEG_INF, KEY_NEG_INF, KEY_NEG_INF);
    for (long i = t0; i < (long)NVOX * 16; i += st) ((uint4*)okeys)[i] = kneg;
    for (long i = t0; i < (long)NVOX * 8; i += st) ((uint4*)xmraw)[i] = kneg;
    for (long i = t0; i < NVOX / 4; i += st) ((int4*)cntv)[i] = make_int4(0, 0, 0, 0);
    for (long i = t0; i < (1024 + 256 * 64 + 256 * 128) / 4; i += st)
        ((float4*)zf)[i] = make_float4(0.f, 0.f, 0.f, 0.f);
    if (t0 < PAD - NPTS) svid[NPTS + t0] = -1;
    if (blockIdx.x == 0 && threadIdx.x < 64) {
        int l = threadIdx.x;
        int lr = l & 15, lk = l >> 4;
        #pragma unroll
        for (int nt = 0; nt < 4; ++nt)
            #pragma unroll
            for (int kt = 0; kt < 2; ++kt) {
                int col = nt * 16 + lr;
                int kb = kt * 32 + lk * 8;
                unsigned u[4];
                #pragma unroll
                for (int j = 0; j < 4; ++j) {
                    float a = w2[(kb + 2 * j) * 64 + col];
                    float b = w2[(kb + 2 * j + 1) * 64 + col];
                    u[j] = packbf(a, b);
                }
                wfrag[(nt * 2 + kt) * 64 + l] = make_uint4(u[0], u[1], u[2], u[3]);
            }
    }
}

__global__ void k_hist(const int* __restrict__ unq, int* __restrict__ cntv) {
    int i = blockIdx.x * blockDim.x + threadIdx.x;
    if (i < NPTS) atomicAdd(&cntv[unq[i]], 1);
}

__global__ void k_scanA(const int* __restrict__ cntv, int* __restrict__ startv,
                        int* __restrict__ bsum) {
    __shared__ int lds[256];
    int t = threadIdx.x;
    int idx4 = blockIdx.x * 256 + t;
    int4 cv = ((const int4*)cntv)[idx4];
    int s0 = cv.x, s1 = s0 + cv.y, s2 = s1 + cv.z, T = s2 + cv.w;
    lds[t] = T;
    __syncthreads();
    for (int o = 1; o < 256; o <<= 1) {
        int v = (t >= o) ? lds[t - o] : 0;
        __syncthreads();
        lds[t] += v;
        __syncthreads();
    }
    int excl = lds[t] - T;
    int4 ov; ov.x = excl; ov.y = excl + s0; ov.z = excl + s1; ov.w = excl + s2;
    ((int4*)startv)[idx4] = ov;
    if (t == 255) bsum[blockIdx.x] = lds[255];
}

// scanC (scanB folded): every block redundantly scans the 256 bsums
__global__ void k_scanC(int* __restrict__ startv, int* __restrict__ offv,
                        const int* __restrict__ bsum) {
    __shared__ int lds[256];
    int t = threadIdx.x;
    int b = bsum[t];
    lds[t] = b;
    __syncthreads();
    for (int o = 1; o < 256; o <<= 1) {
        int v = (t >= o) ? lds[t - o] : 0;
        __syncthreads();
        lds[t] += v;
        __syncthreads();
    }
    int add = (blockIdx.x > 0) ? lds[blockIdx.x - 1] : 0;
    int idx4 = blockIdx.x * 256 + t;
    int4 v = ((int4*)startv)[idx4];
    v.x += add; v.y += add; v.z += add; v.w += add;
    ((int4*)startv)[idx4] = v;
    ((int4*)offv)[idx4] = v;
}

// scatter point payload (16B sector) only; svid is generated densely later
__global__ void k_scatterp(const float* __restrict__ xyz, const float* __restrict__ pf,
                           const int* __restrict__ unq, int* __restrict__ offv,
                           float4* __restrict__ spts) {
    int i = blockIdx.x * blockDim.x + threadIdx.x;
    if (i >= NPTS) return;
    int v = unq[i];
    int pos = atomicAdd(&offv[v], 1);
    float4 p;
    p.x = xyz[3 * i + 0]; p.y = xyz[3 * i + 1]; p.z = xyz[3 * i + 2]; p.w = pf[i];
    spts[pos] = p;
}

// fused: dense svid fill + per-voxel xyz mean (dense spts reads)
__global__ void k_vmfill(const float4* __restrict__ spts, const int* __restrict__ cntv,
                         const int* __restrict__ startv, int* __restrict__ svid,
                         float4* __restrict__ vmeanv) {
    int v = blockIdx.x * 256 + threadIdx.x;
    int cnt = cntv[v];
    if (!cnt) return;
    int st = startv[v];
    float sx = 0, sy = 0, sz = 0;
    for (int j = 0; j < cnt; ++j) {
        float4 p = spts[st + j];
        sx += p.x; sy += p.y; sz += p.z;
        svid[st + j] = v;
    }
    float inv = 1.0f / (float)cnt;
    vmeanv[v] = make_float4(sx * inv, sy * inv, sz * inv, 0.f);
}

__device__ __forceinline__ void flush32(int v, float m, bool atom, int c,
                                        unsigned* __restrict__ xm) {
    if ((unsigned)v >= (unsigned)NVOX) return;
    if (atom) atomicMax(&xm[(size_t)v * 32 + c], fkey(m));
    else xm[(size_t)v * 32 + c] = fkey(m);
}
__device__ __forceinline__ void flush64(int v, float m, bool atom, int c,
                                        unsigned* __restrict__ ok) {
    if ((unsigned)v >= (unsigned)NVOX) return;
    if (atom) atomicMax(&ok[(size_t)v * 64 + c], fkey(m));
    else ok[(size_t)v * 64 + c] = fkey(m);
}

// passA: per-wave; 2 lanes/row x 16 ch -> y1 f32; store y1 bf16 to global;
// LDS transpose tile -> segmented scan (unconditional shfl: all lanes active)
__global__ __launch_bounds__(256) void k_passA(
    const float4* __restrict__ spts, const int* __restrict__ svid,
    const float4* __restrict__ vmeanv, const float* __restrict__ w1,
    unsigned* __restrict__ xmraw, unsigned* __restrict__ y1bf,
    float* __restrict__ spart1) {
    __shared__ float ylds[4][32 * 33];
    int t = threadIdx.x;
    int lane = t & 63, wave = t >> 6;
    int rl = lane & 31, half = lane >> 5;
    long grow = (long)blockIdx.x * 128 + wave * 32 + rl;
    int vid = svid[grow];
    float yv[16];
    #pragma unroll
    for (int j = 0; j < 16; ++j) yv[j] = 0.f;
    if (vid >= 0) {
        float4 p = spts[grow];
        float4 vm = vmeanv[vid];
        float f[11];
        make_feat(p.x, p.y, p.z, p.w, vm.x, vm.y, vm.z, f);
        const float4* w1f = (const float4*)w1;
        #pragma unroll
        for (int k = 0; k < 11; ++k) {
            float fk = f[k];
            #pragma unroll
            for (int q = 0; q < 4; ++q) {
                float4 wq = w1f[k * 8 + half * 4 + q];
                yv[4 * q + 0] = fmaf(fk, wq.x, yv[4 * q + 0]);
                yv[4 * q + 1] = fmaf(fk, wq.y, yv[4 * q + 1]);
                yv[4 * q + 2] = fmaf(fk, wq.z, yv[4 * q + 2]);
                yv[4 * q + 3] = fmaf(fk, wq.w, yv[4 * q + 3]);
            }
        }
    }
    {
        unsigned ypk[8];
        #pragma unroll
        for (int q = 0; q < 8; ++q) ypk[q] = packbf(yv[2 * q], yv[2 * q + 1]);
        uint4* yb = (uint4*)y1bf;
        yb[grow * 4 + half * 2 + 0] = *(const uint4*)&ypk[0];
        yb[grow * 4 + half * 2 + 1] = *(const uint4*)&ypk[4];
    }
    float* yw = &ylds[wave][0];
    #pragma unroll
    for (int j = 0; j < 16; ++j) yw[rl * 33 + half * 16 + j] = yv[j];
    asm volatile("s_waitcnt lgkmcnt(0)" ::: "memory");
    __builtin_amdgcn_sched_barrier(0);
    int c = rl;
    int r0 = half * 16;
    float sa = 0.f, sq = 0.f;
    int cur_v = -2; float cur_m = 0.f; bool first = true;
    #pragma unroll
    for (int i = 0; i < 16; ++i) {
        int r = r0 + i;
        float y = yw[r * 33 + c];
        int v = __shfl(vid, r);   // unconditional: all lanes active
        sa += y; sq += y * y;
        if (i == 0) { cur_v = v; cur_m = y; }
        else if (v == cur_v) cur_m = fmaxf(cur_m, y);
        else {
            flush32(cur_v, cur_m, first, c, xmraw);
            first = false; cur_v = v; cur_m = y;
        }
    }
    flush32(cur_v, cur_m, true, c, xmraw);
    sa += __shfl_xor(sa, 32);
    sq += __shfl_xor(sq, 32);
    if (half == 0) {
        int slot = (blockIdx.x * 4 + wave) & 255;
        atomicAdd(&spart1[slot * 64 + c], sa);
        atomicAdd(&spart1[slot * 64 + 32 + c], sq);
    }
}

__global__ void k_fin1(const float* __restrict__ spart1, float* __restrict__ stats,
                       const float* __restrict__ g1, const float* __restrict__ b1) {
    __shared__ float cs[64];
    int t = threadIdx.x;
    float s = 0.f;
    for (int r = 0; r < 256; ++r) s += spart1[r * 64 + t];
    cs[t] = s;
    __syncthreads();
    if (t < 32) {
        float invn = 1.0f / (float)NPTS;
        float mu = cs[t] * invn;
        float var = cs[32 + t] * invn - mu * mu;
        float sc = rsqrtf(var + BN_EPS) * g1[t];
        stats[64 + t] = sc;
        stats[96 + t] = b1[t] - mu * sc;
    }
}

// per-voxel: zxm = packed bf16 of relu(affine(xm))
__global__ void k_xmz(const unsigned* __restrict__ xmraw,
                      const float* __restrict__ stats, unsigned* __restrict__ zxm) {
    int tid = blockIdx.x * 256 + threadIdx.x;  // NVOX*4
    int v = tid >> 2, q = tid & 3;             // channels 8q..8q+7
    uint4 a = ((const uint4*)xmraw)[v * 8 + q * 2];
    uint4 b = ((const uint4*)xmraw)[v * 8 + q * 2 + 1];
    float4 sc0 = ((const float4*)(stats + 64))[q * 2];
    float4 sh0 = ((const float4*)(stats + 96))[q * 2];
    float4 sc1 = ((const float4*)(stats + 64))[q * 2 + 1];
    float4 sh1 = ((const float4*)(stats + 96))[q * 2 + 1];
    uint4 o;
    o.x = packbf(fmaxf(0.f, fmaf(funkey(a.x), sc0.x, sh0.x)),
                 fmaxf(0.f, fmaf(funkey(a.y), sc0.y, sh0.y)));
    o.y = packbf(fmaxf(0.f, fmaf(funkey(a.z), sc0.z, sh0.z)),
                 fmaxf(0.f, fmaf(funkey(a.w), sc0.w, sh0.w)));
    o.z = packbf(fmaxf(0.f, fmaf(funkey(b.x), sc1.x, sh1.x)),
                 fmaxf(0.f, fmaf(funkey(b.y), sc1.y, sh1.y)));
    o.w = packbf(fmaxf(0.f, fmaf(funkey(b.z), sc1.z, sh1.z)),
                 fmaxf(0.f, fmaf(funkey(b.w), sc1.w, sh1.w)));
    ((uint4*)zxm)[v * 4 + q] = o;
}

// k_l2: load y1 bf16 + prepacked zxm -> per-wave Abuf -> MFMA -> y2t (aliased)
// -> boundary-mask segmented max (wave-uniform branch) + BN2 partials.
__global__ __launch_bounds__(256) void k_l2(
    const int* __restrict__ svid, const unsigned* __restrict__ y1bf,
    const unsigned* __restrict__ zxm, const uint4* __restrict__ wfrag,
    const float* __restrict__ stats, float* __restrict__ spart2,
    unsigned* __restrict__ okeys) {
    __shared__ unsigned shbuf[4][1088];   // Abuf [32][32] then y2t [64][17]
    int t = threadIdx.x;
    int lane = t & 63, wave = t >> 6;
    int rl = lane & 31, half = lane >> 5;
    int lr = lane & 15, lk = lane >> 4;
    long brow = (long)blockIdx.x * 128 + wave * 32;
    int vid = svid[brow + rl];
    int vprev = __shfl(vid, (lane + 63) & 63);
    unsigned mask32 = (unsigned)(__ballot(rl > 0 && vid != vprev) & 0xFFFFFFFFull);

    uint4 bw[8];
    #pragma unroll
    for (int q = 0; q < 8; ++q) bw[q] = wfrag[q * 64 + lane];
    uint4 yu0 = ((const uint4*)y1bf)[(brow + rl) * 4 + half * 2];
    uint4 yu1 = ((const uint4*)y1bf)[(brow + rl) * 4 + half * 2 + 1];
    uint4 xa = make_uint4(0, 0, 0, 0), xb = make_uint4(0, 0, 0, 0);
    if (vid >= 0) {
        xa = ((const uint4*)zxm)[(size_t)vid * 4 + half * 2];
        xb = ((const uint4*)zxm)[(size_t)vid * 4 + half * 2 + 1];
    }

    unsigned zpk[8];
    if (vid >= 0) {
        unsigned yw[8] = {yu0.x, yu0.y, yu0.z, yu0.w, yu1.x, yu1.y, yu1.z, yu1.w};
        #pragma unroll
        for (int q = 0; q < 4; ++q) {
            float4 sc = ((const float4*)(stats + 64))[half * 4 + q];
            float4 sh = ((const float4*)(stats + 96))[half * 4 + q];
            float yA = bf2f((unsigned short)(yw[2 * q] & 0xFFFF));
            float yB = bf2f((unsigned short)(yw[2 * q] >> 16));
            float yC = bf2f((unsigned short)(yw[2 * q + 1] & 0xFFFF));
            float yD = bf2f((unsigned short)(yw[2 * q + 1] >> 16));
            zpk[2 * q + 0] = packbf(fmaxf(0.f, fmaf(yA, sc.x, sh.x)),
                                    fmaxf(0.f, fmaf(yB, sc.y, sh.y)));
            zpk[2 * q + 1] = packbf(fmaxf(0.f, fmaf(yC, sc.z, sh.z)),
                                    fmaxf(0.f, fmaf(yD, sc.w, sh.w)));
        }
    } else {
        #pragma unroll
        for (int q = 0; q < 8; ++q) zpk[q] = 0u;
    }
    {
        uint4* arow = (uint4*)&shbuf[wave][rl * 32];
        int sw = rl & 7;
        arow[(2 * half + 0) ^ sw] = *(const uint4*)&zpk[0];
        arow[(2 * half + 1) ^ sw] = *(const uint4*)&zpk[4];
        arow[(4 + 2 * half) ^ sw] = xa;
        arow[(5 + 2 * half) ^ sw] = xb;
    }
    asm volatile("s_waitcnt lgkmcnt(0)" ::: "memory");
    __builtin_amdgcn_sched_barrier(0);

    bf16x8 afr[2][2];
    #pragma unroll
    for (int mt = 0; mt < 2; ++mt)
        #pragma unroll
        for (int kt = 0; kt < 2; ++kt) {
            int riw = mt * 16 + lr;
            uint4 uu = ((const uint4*)&shbuf[wave][riw * 32])[(kt * 4 + lk) ^ (riw & 7)];
            afr[mt][kt] = __builtin_bit_cast(bf16x8, uu);
        }
    asm volatile("s_waitcnt lgkmcnt(0)" ::: "memory");
    __builtin_amdgcn_sched_barrier(0);

    f32x4 acc[2][4];
    #pragma unroll
    for (int mt = 0; mt < 2; ++mt)
        #pragma unroll
        for (int nt = 0; nt < 4; ++nt) {
            acc[mt][nt] = (f32x4){0.f, 0.f, 0.f, 0.f};
            #pragma unroll
            for (int kt = 0; kt < 2; ++kt)
                acc[mt][nt] = __builtin_amdgcn_mfma_f32_16x16x32_bf16(
                    afr[mt][kt], __builtin_bit_cast(bf16x8, bw[nt * 2 + kt]),
                    acc[mt][nt], 0, 0, 0);
        }

    unsigned* y2w = &shbuf[wave][0];
    #pragma unroll
    for (int mt = 0; mt < 2; ++mt)
        #pragma unroll
        for (int nt = 0; nt < 4; ++nt) {
            int col = nt * 16 + lr;
            int w0 = mt * 8 + lk * 2;
            y2w[col * 17 + w0] = packbf(acc[mt][nt][0], acc[mt][nt][1]);
            y2w[col * 17 + w0 + 1] = packbf(acc[mt][nt][2], acc[mt][nt][3]);
        }

    {
        float sa[4] = {0.f, 0.f, 0.f, 0.f}, sq[4] = {0.f, 0.f, 0.f, 0.f};
        #pragma unroll
        for (int mt = 0; mt < 2; ++mt)
            #pragma unroll
            for (int nt = 0; nt < 4; ++nt)
                #pragma unroll
                for (int e = 0; e < 4; ++e) {
                    float v = acc[mt][nt][e];
                    sa[nt] += v; sq[nt] += v * v;
                }
        #pragma unroll
        for (int nt = 0; nt < 4; ++nt) {
            sa[nt] += __shfl_xor(sa[nt], 16); sa[nt] += __shfl_xor(sa[nt], 32);
            sq[nt] += __shfl_xor(sq[nt], 16); sq[nt] += __shfl_xor(sq[nt], 32);
        }
        if (lk == 0) {
            int slot = (blockIdx.x * 4 + wave) & 255;
            #pragma unroll
            for (int nt = 0; nt < 4; ++nt) {
                atomicAdd(&spart2[slot * 128 + nt * 16 + lr], sa[nt]);
                atomicAdd(&spart2[slot * 128 + 64 + nt * 16 + lr], sq[nt]);
            }
        }
    }
    asm volatile("s_waitcnt lgkmcnt(0)" ::: "memory");
    __builtin_amdgcn_sched_barrier(0);

    {
        int c = lane;
        float cur_m = 0.f; bool first = true;
        #pragma unroll
        for (int q = 0; q < 16; ++q) {
            unsigned u = y2w[c * 17 + q];
            #pragma unroll
            for (int e = 0; e < 2; ++e) {
                int r = 2 * q + e;
                float d = bf2f((unsigned short)(e ? (u >> 16) : (u & 0xFFFF)));
                if (r == 0) cur_m = d;
                else if ((mask32 >> r) & 1u) {
                    int v = __shfl(vid, r - 1);   // uniform branch: all lanes active
                    flush64(v, cur_m, first, c, okeys);
                    first = false; cur_m = d;
                } else cur_m = fmaxf(cur_m, d);
            }
        }
        int vlast = __shfl(vid, 31);
        flush64(vlast, cur_m, true, c, okeys);
    }
}

__global__ void k_fin2(const float* __restrict__ spart2, float* __restrict__ stats,
                       const float* __restrict__ g2, const float* __restrict__ b2) {
    __shared__ float cs[128];
    int t = threadIdx.x;
    float s = 0.f;
    for (int r = 0; r < 256; ++r) s += spart2[r * 128 + t];
    cs[t] = s;
    __syncthreads();
    if (t < 64) {
        float invn = 1.0f / (float)NPTS;
        float mu = cs[t] * invn;
        float var = cs[64 + t] * invn - mu * mu;
        float sc = rsqrtf(var + BN_EPS) * g2[t];
        stats[256 + t] = sc;
        stats[320 + t] = b2[t] - mu * sc;
    }
}

__global__ void k_out(unsigned* __restrict__ okeys, const float* __restrict__ stats) {
    int i4 = blockIdx.x * 256 + threadIdx.x;  // < NVOX*16
    uint4 u = ((const uint4*)okeys)[i4];
    int c0 = (i4 & 15) * 4;
    float4 o;
    o.x = fmaxf(0.f, fmaf(funkey(u.x), stats[256 + c0 + 0], stats[320 + c0 + 0]));
    o.y = fmaxf(0.f, fmaf(funkey(u.y), stats[256 + c0 + 1], stats[320 + c0 + 1]));
    o.z = fmaxf(0.f, fmaf(funkey(u.z), stats[256 + c0 + 2], stats[320 + c0 + 2]));
    o.w = fmaxf(0.f, fmaf(funkey(u.w), stats[256 + c0 + 3], stats[320 + c0 + 3]));
    ((float4*)okeys)[i4] = o;
}

extern "C" void kernel_launch(void* const* d_in, const int* in_sizes, int n_in,
                              void* d_out, int out_size, void* d_ws, size_t ws_size,
                              hipStream_t stream) {
    const float* xyz = (const float*)d_in[0];
    const float* pf  = (const float*)d_in[1];
    const float* w1  = (const float*)d_in[2];
    const float* g1  = (const float*)d_in[3];
    const float* b1  = (const float*)d_in[4];
    const float* w2  = (const float*)d_in[5];
    const float* g2  = (const float*)d_in[6];
    const float* b2  = (const float*)d_in[7];
    const int*   unq = (const int*)d_in[8];

    float4* spts     = (float4*)d_ws;                        // PAD float4 (24 MB)
    float4* vmeanv   = spts + PAD;                           // NVOX float4 (4 MB)
    int* svid        = (int*)(vmeanv + NVOX);                // PAD ints (6 MB)
    unsigned* xmraw  = (unsigned*)(svid + PAD);              // NVOX*32 f32-fkeys (32 MB)
    int* cntv        = (int*)(xmraw + (size_t)NVOX * 32);    // NVOX
    int* startv      = cntv + NVOX;                          // NVOX
    int* offv        = startv + NVOX;                        // NVOX
    int* bsum        = offv + NVOX;                          // 256
    float* stats     = (float*)(bsum + 256);                 // 1024
    float* spart1    = stats + 1024;                         // 256*64
    float* spart2    = spart1 + 256 * 64;                    // 256*128
    uint4* wfrag     = (uint4*)(spart2 + 256 * 128);         // 8*64 uint4
    unsigned* y1bf   = (unsigned*)(wfrag + 512);             // PAD*16 uints (96 MB)
    // zxm (16 MB) aliases spts (24 MB): spts dead after k_passA; k_xmz runs
    // after k_fin1 (stream-serial). Proven in R11.
    unsigned* zxm    = (unsigned*)spts;

    unsigned* okeys = (unsigned*)d_out;

    k_init<<<2048, 256, 0, stream>>>(okeys, xmraw, cntv, stats, svid, w2, wfrag);
    k_hist<<<NB_PT, 256, 0, stream>>>(unq, cntv);
    k_scanA<<<256, 256, 0, stream>>>(cntv, startv, bsum);
    k_scanC<<<256, 256, 0, stream>>>(startv, offv, bsum);
    k_scatterp<<<NB_PT, 256, 0, stream>>>(xyz, pf, unq, offv, spts);
    k_vmfill<<<NVOX / 256, 256, 0, stream>>>(spts, cntv, startv, svid, vmeanv);
    k_passA<<<NB_L2, 256, 0, stream>>>(spts, svid, vmeanv, w1, xmraw, y1bf, spart1);
    k_fin1<<<1, 64, 0, stream>>>(spart1, stats, g1, b1);
    k_xmz<<<NVOX * 4 / 256, 256, 0, stream>>>(xmraw, stats, zxm);
    k_l2<<<NB_L2, 256, 0, stream>>>(svid, y1bf, zxm, wfrag, stats, spart2, okeys);
    k_fin2<<<1, 128, 0, stream>>>(spart2, stats, g2, b2);
    k_out<<<NVOX * 16 / 256, 256, 0, stream>>>(okeys, stats);
}